// Round 1
// baseline (187.721 us; speedup 1.0000x reference)
//
#include <hip/hip_runtime.h>

// PRNN: GRU(NH=128, T=32 steps, P=2-bit inputs) + MLP head (128->128->4) + log-softmax gather.
// B=16384 sequences. Strategy: 1 block (8 waves, 512 thr) per 64-sequence tile, grid=256.
// bf16 MFMA 16x16x32, orientation C[j][b]: A=weights (w_hh from swizzled LDS, w1/w2 in regs),
// B=h from swizzled LDS [b][128] bf16. h round-trips LDS each step (fragment transpose).
// Input-side gate projection has only 4 variants (2-bit patches) -> 6KB LDS table.

#define LSEQ   64
#define NSTEP  32
#define BT     64     // batch tile per block
#define BLK    512    // 8 waves

using s8v = __attribute__((ext_vector_type(8))) short;   // 8 x bf16 (4 VGPR)
using f4v = __attribute__((ext_vector_type(4))) float;   // MFMA accumulator

__device__ __forceinline__ unsigned f2bf1(float f) {
  unsigned u = __builtin_bit_cast(unsigned, f);
  u += 0x7fffu + ((u >> 16) & 1u);      // RNE
  return u >> 16;
}
__device__ __forceinline__ unsigned pack2(float a, float b) {
  return f2bf1(a) | (f2bf1(b) << 16);
}
__device__ __forceinline__ s8v pack8(float4 u, float4 v) {
  s8v a;
  a[0] = (short)f2bf1(u.x); a[1] = (short)f2bf1(u.y);
  a[2] = (short)f2bf1(u.z); a[3] = (short)f2bf1(u.w);
  a[4] = (short)f2bf1(v.x); a[5] = (short)f2bf1(v.y);
  a[6] = (short)f2bf1(v.z); a[7] = (short)f2bf1(v.w);
  return a;
}
__device__ __forceinline__ f4v mfma16(s8v a, s8v b, f4v c) {
  return __builtin_amdgcn_mfma_f32_16x16x32_bf16(a, b, c, 0, 0, 0);
}
__device__ __forceinline__ float sigm(float x) {
  x = fminf(fmaxf(x, -30.f), 30.f);
  return 1.f / (1.f + __expf(-x));
}
__device__ __forceinline__ float tanhc(float x) {
  x = fminf(fmaxf(x, -15.f), 15.f);
  float e = __expf(-2.f * x);
  return (1.f - e) / (1.f + e);
}

__global__ __launch_bounds__(BLK, 2) void prnn_kernel(
    const float* __restrict__ x, const float* __restrict__ w_ih,
    const float* __restrict__ w_hh, const float* __restrict__ b_ih,
    const float* __restrict__ b_hh, const float* __restrict__ w1,
    const float* __restrict__ b1, const float* __restrict__ w2,
    const float* __restrict__ b2, float* __restrict__ out) {

  // LDS: 96K whh + 16K h + 16K hid + 6K xi + 2K idx = 138.25 KB
  __shared__ __align__(16) unsigned char lds_whh[384 * 128 * 2]; // bf16, row-swizzled
  __shared__ __align__(16) unsigned char lds_h[64 * 128 * 2];    // bf16 [b][k], b-swizzled
  __shared__ __align__(16) unsigned char lds_hid[64 * 128 * 2];  // bf16 [b][k], b-swizzled
  __shared__ __align__(16) float lds_xi[96 * 4 * 4];             // [quad][var][4] fp32
  __shared__ unsigned char lds_idx[64 * 32];                     // patch idx per (b,t)

  const int tid = threadIdx.x;
  const int bbase = blockIdx.x * BT;

  // ---- init: patch indices (little-endian 2-bit) ----
  {
    int b = tid >> 3, ch = tid & 7;
    const float* xp = x + (size_t)(bbase + b) * LSEQ + ch * 8;
    unsigned pk = 0;
    #pragma unroll
    for (int i = 0; i < 4; ++i) {
      unsigned v = (xp[2 * i] != 0.f ? 1u : 0u) | (xp[2 * i + 1] != 0.f ? 2u : 0u);
      pk |= v << (8 * i);
    }
    *(unsigned*)&lds_idx[b * 32 + ch * 4] = pk;
  }
  // ---- init: xi table. r,z rows fold b_ih+b_hh; n rows fold only b_ih
  //      (b_hh_n must be multiplied by r -> kept in regs) ----
  for (int j = tid; j < 384; j += BLK) {
    float base = b_ih[j] + (j < 256 ? b_hh[j] : 0.f);
    float wa = w_ih[2 * j], wb = w_ih[2 * j + 1];
    int q = j >> 2, e = j & 3;
    #pragma unroll
    for (int v = 0; v < 4; ++v)
      lds_xi[(q * 4 + v) * 4 + e] = base + ((v & 1) ? wa : 0.f) + ((v & 2) ? wb : 0.f);
  }
  // ---- init: w_hh fp32 -> bf16 LDS, XOR-swizzled byte ^= (row&7)<<4 ----
  for (int i = tid; i < 384 * 32; i += BLK) {
    int j = i >> 5, kq = i & 31;
    const float4 wv = *(const float4*)(w_hh + j * 128 + kq * 4);
    uint2 pkd;
    pkd.x = pack2(wv.x, wv.y);
    pkd.y = pack2(wv.z, wv.w);
    unsigned byteo = (unsigned)(j * 256 + kq * 8) ^ (unsigned)((j & 7) << 4);
    *(uint2*)&lds_whh[byteo] = pkd;
  }
  // ---- init: zero h ----
  for (int i = tid; i < 64 * 128 / 2; i += BLK) ((unsigned*)lds_h)[i] = 0u;

  const int lane = tid & 63;
  const int wid = __builtin_amdgcn_readfirstlane((int)(tid >> 6));
  const int js = wid & 3;        // j-slice [32*js, 32*js+32)
  const int bh = wid >> 2;       // batch half (32 each)
  const int lg = lane >> 4;      // k-group within fragment
  const int ln = lane & 15;      // row/col within 16-tile
  const unsigned xorc = (unsigned)((ln & 7) << 4);   // swizzle const (row&7 == ln&7 here)

  // ---- per-lane register preloads: w1/w2 A-fragments, biases ----
  s8v wA1[2][4];
  float b1f[2][4], bhn[2][4];
  #pragma unroll
  for (int p = 0; p < 2; ++p) {
    int j2 = 16 * (2 * js + p) + ln;
    #pragma unroll
    for (int ks = 0; ks < 4; ++ks) {
      const float* src = w1 + j2 * 128 + ks * 32 + lg * 8;
      wA1[p][ks] = pack8(*(const float4*)src, *(const float4*)(src + 4));
    }
    #pragma unroll
    for (int r = 0; r < 4; ++r) {
      int jrow = 16 * (2 * js + p) + 4 * lg + r;
      b1f[p][r] = b1[jrow];
      bhn[p][r] = b_hh[256 + jrow];
    }
  }
  s8v wA2[4];
  #pragma unroll
  for (int ks = 0; ks < 4; ++ks) {
    s8v a; 
    #pragma unroll
    for (int e = 0; e < 8; ++e) a[e] = (short)0;
    if (ln < 4) {
      const float* src = w2 + ln * 128 + ks * 32 + lg * 8;
      a = pack8(*(const float4*)src, *(const float4*)(src + 4));
    }
    wA2[ks] = a;
  }
  float b2r[4];
  #pragma unroll
  for (int r = 0; r < 4; ++r) {
    int c = 4 * lg + r;
    b2r[r] = (c < 4) ? b2[c] : 0.f;
  }

  f4v hfr[2][2];   // resident h in C-fragment layout (rows = this wave's j-slice)
  #pragma unroll
  for (int p = 0; p < 2; ++p)
    #pragma unroll
    for (int nt = 0; nt < 2; ++nt) {
      hfr[p][nt][0] = 0.f; hfr[p][nt][1] = 0.f; hfr[p][nt][2] = 0.f; hfr[p][nt][3] = 0.f;
    }
  float lp0 = 0.f, lp1 = 0.f;
  int pv0 = 0, pv1 = 0;

  __syncthreads();

  for (int t = 0; t < NSTEP; ++t) {
    // ---- P1: gh = W_hh * h  (B-frags from lds_h, A-frags from lds_whh) ----
    s8v Bf[4][2];
    #pragma unroll
    for (int ks = 0; ks < 4; ++ks)
      #pragma unroll
      for (int nt = 0; nt < 2; ++nt) {
        int b = 16 * (2 * bh + nt) + ln;
        Bf[ks][nt] = *(const s8v*)&lds_h[(unsigned)(b * 256 + ks * 64 + lg * 16) ^ xorc];
      }
    f4v acc[6][2];
    #pragma unroll
    for (int m = 0; m < 6; ++m)
      #pragma unroll
      for (int nt = 0; nt < 2; ++nt) {
        acc[m][nt][0] = 0.f; acc[m][nt][1] = 0.f; acc[m][nt][2] = 0.f; acc[m][nt][3] = 0.f;
      }
    #pragma unroll
    for (int mtl = 0; mtl < 6; ++mtl) {
      int mt = 8 * (mtl >> 1) + 2 * js + (mtl & 1);   // r:0-7, z:8-15, n:16-23
      unsigned rowo = (unsigned)((16 * mt + ln) * 256);
      #pragma unroll
      for (int ks = 0; ks < 4; ++ks) {
        s8v A = *(const s8v*)&lds_whh[(rowo + (unsigned)(ks * 64 + lg * 16)) ^ xorc];
        acc[mtl][0] = mfma16(A, Bf[ks][0], acc[mtl][0]);
        acc[mtl][1] = mfma16(A, Bf[ks][1], acc[mtl][1]);
      }
    }
    // ---- P2: gates (fp32) ----
    uint2 hw[2][2];
    #pragma unroll
    for (int p = 0; p < 2; ++p) {
      int q0 = 4 * (2 * js + p) + lg;
      #pragma unroll
      for (int nt = 0; nt < 2; ++nt) {
        int var = nt ? pv1 : pv0;
        const f4v xr = *(const f4v*)&lds_xi[(q0 * 4 + var) * 4];
        const f4v xz = *(const f4v*)&lds_xi[((q0 + 32) * 4 + var) * 4];
        const f4v xn = *(const f4v*)&lds_xi[((q0 + 64) * 4 + var) * 4];
        f4v hn;
        #pragma unroll
        for (int r = 0; r < 4; ++r) {
          float R  = sigm(acc[p][nt][r] + xr[r]);
          float Z  = sigm(acc[2 + p][nt][r] + xz[r]);
          float Ng = tanhc(xn[r] + R * (acc[4 + p][nt][r] + bhn[p][r]));
          float ho = hfr[p][nt][r];
          hn[r] = Z * (ho - Ng) + Ng;        // (1-z)*n + z*h
        }
        hfr[p][nt] = hn;
        hw[p][nt].x = pack2(hn[0], hn[1]);
        hw[p][nt].y = pack2(hn[2], hn[3]);
      }
    }
    __syncthreads();   // all P1 reads of lds_h done
    // ---- P3: write h_new (each wave: its j-slice x its batch half) ----
    #pragma unroll
    for (int p = 0; p < 2; ++p) {
      unsigned co = (unsigned)(32 * (2 * js + p) + 8 * lg);
      #pragma unroll
      for (int nt = 0; nt < 2; ++nt) {
        int b = 16 * (2 * bh + nt) + ln;
        *(uint2*)&lds_h[(unsigned)(b * 256 + co) ^ xorc] = hw[p][nt];
      }
    }
    __syncthreads();   // h complete
    // ---- P4: hid = relu(W1*h + b1) ----
    s8v Bf2[4][2];
    #pragma unroll
    for (int ks = 0; ks < 4; ++ks)
      #pragma unroll
      for (int nt = 0; nt < 2; ++nt) {
        int b = 16 * (2 * bh + nt) + ln;
        Bf2[ks][nt] = *(const s8v*)&lds_h[(unsigned)(b * 256 + ks * 64 + lg * 16) ^ xorc];
      }
    f4v hacc[2][2];
    #pragma unroll
    for (int p = 0; p < 2; ++p)
      #pragma unroll
      for (int nt = 0; nt < 2; ++nt) {
        hacc[p][nt][0] = b1f[p][0]; hacc[p][nt][1] = b1f[p][1];
        hacc[p][nt][2] = b1f[p][2]; hacc[p][nt][3] = b1f[p][3];
      }
    #pragma unroll
    for (int p = 0; p < 2; ++p)
      #pragma unroll
      for (int ks = 0; ks < 4; ++ks) {
        s8v A = wA1[p][ks];
        hacc[p][0] = mfma16(A, Bf2[ks][0], hacc[p][0]);
        hacc[p][1] = mfma16(A, Bf2[ks][1], hacc[p][1]);
      }
    #pragma unroll
    for (int p = 0; p < 2; ++p) {
      unsigned co = (unsigned)(32 * (2 * js + p) + 8 * lg);
      #pragma unroll
      for (int nt = 0; nt < 2; ++nt) {
        int b = 16 * (2 * bh + nt) + ln;
        f4v hv = hacc[p][nt];
        uint2 wv;
        wv.x = pack2(fmaxf(hv[0], 0.f), fmaxf(hv[1], 0.f));
        wv.y = pack2(fmaxf(hv[2], 0.f), fmaxf(hv[3], 0.f));
        *(uint2*)&lds_hid[(unsigned)(b * 256 + co) ^ xorc] = wv;
      }
    }
    __syncthreads();   // hid complete
    // ---- P5: logits (js==0 waves only), in-register softmax over 4 classes ----
    int b0 = 32 * bh + ln;
    int b1x = b0 + 16;
    int ic0 = (int)lds_idx[b0 * 32 + t];
    int ic1 = (int)lds_idx[b1x * 32 + t];
    if (js == 0) {
      f4v lacc[2];
      #pragma unroll
      for (int nt = 0; nt < 2; ++nt) {
        lacc[nt][0] = b2r[0]; lacc[nt][1] = b2r[1];
        lacc[nt][2] = b2r[2]; lacc[nt][3] = b2r[3];
      }
      #pragma unroll
      for (int ks = 0; ks < 4; ++ks)
        #pragma unroll
        for (int nt = 0; nt < 2; ++nt) {
          int b = 16 * (2 * bh + nt) + ln;
          s8v Bh = *(const s8v*)&lds_hid[(unsigned)(b * 256 + ks * 64 + lg * 16) ^ xorc];
          lacc[nt] = mfma16(wA2[ks], Bh, lacc[nt]);
        }
      if (lg == 0) {   // rows 0..3 == classes live in regs of lanes 0..15
        #pragma unroll
        for (int nt = 0; nt < 2; ++nt) {
          float l0 = lacc[nt][0], l1 = lacc[nt][1], l2 = lacc[nt][2], l3 = lacc[nt][3];
          float mx = fmaxf(fmaxf(l0, l1), fmaxf(l2, l3));
          float s = __expf(l0 - mx) + __expf(l1 - mx) + __expf(l2 - mx) + __expf(l3 - mx);
          int ii = nt ? ic1 : ic0;
          float sel = (ii == 0) ? l0 : (ii == 1) ? l1 : (ii == 2) ? l2 : l3;
          float v = sel - mx - __logf(s);
          if (nt) lp1 += v; else lp0 += v;
        }
      }
    }
    pv0 = ic0; pv1 = ic1;   // teacher-forcing input for step t+1
  }

  if (js == 0 && lg == 0) {
    out[bbase + 32 * bh + ln] = lp0;
    out[bbase + 32 * bh + 16 + ln] = lp1;
  }
}

extern "C" void kernel_launch(void* const* d_in, const int* in_sizes, int n_in,
                              void* d_out, int out_size, void* d_ws, size_t ws_size,
                              hipStream_t stream) {
  const float* x    = (const float*)d_in[0];
  const float* w_ih = (const float*)d_in[1];
  const float* w_hh = (const float*)d_in[2];
  const float* b_ih = (const float*)d_in[3];
  const float* b_hh = (const float*)d_in[4];
  const float* w1   = (const float*)d_in[5];
  const float* b1   = (const float*)d_in[6];
  const float* w2   = (const float*)d_in[7];
  const float* b2   = (const float*)d_in[8];
  float* out = (float*)d_out;
  int B = in_sizes[0] / LSEQ;     // 16384
  int grid = B / BT;              // 256
  prnn_kernel<<<grid, BLK, 0, stream>>>(x, w_ih, w_hh, b_ih, b_hh, w1, b1, w2, b2, out);
}

// Round 2
// 105.445 us; speedup vs baseline: 1.7803x; 1.7803x over previous
//
#include <hip/hip_runtime.h>
#include <hip/hip_bf16.h>

// PRNN R2: GRU(NH=128, T=32) + MLP head, B=16384.
// 4 waves (256 thr) per 32-seq tile, grid=512, 2 blocks/CU (LDS 67.5KB, VGPR<=256).
// w_hh(r,z) + w1 A-frags in VGPRs; w_hh(n), w2 in LDS in FRAGMENT ORDER (conflict-free
// ds_read_b128 at base+lane*16). h/hid in frag-order LDS; h B-frags register-carried
// P4(t)->P1(t+1). xi (4 input variants) folded into MFMA C-init. 2 barriers/step.

#define NSTEP 32
#define BT    32
#define BLK   256

using s8v = __attribute__((ext_vector_type(8))) short;   // 8 bf16
using f4v = __attribute__((ext_vector_type(4))) float;   // MFMA acc

#define L2E 1.4426950408889634f
#define LN2 0.6931471805599453f

__device__ __forceinline__ unsigned short f2bf(float f) {
  __hip_bfloat16 h = __float2bfloat16(f);
  return __builtin_bit_cast(unsigned short, h);
}
__device__ __forceinline__ unsigned pkbf2(float a, float b) {
  return (unsigned)f2bf(a) | ((unsigned)f2bf(b) << 16);
}
__device__ __forceinline__ s8v pack8(float4 u, float4 v) {
  s8v a;
  a[0]=(short)f2bf(u.x); a[1]=(short)f2bf(u.y); a[2]=(short)f2bf(u.z); a[3]=(short)f2bf(u.w);
  a[4]=(short)f2bf(v.x); a[5]=(short)f2bf(v.y); a[6]=(short)f2bf(v.z); a[7]=(short)f2bf(v.w);
  return a;
}
__device__ __forceinline__ f4v mfma16(s8v a, s8v b, f4v c) {
  return __builtin_amdgcn_mfma_f32_16x16x32_bf16(a, b, c, 0, 0, 0);
}
// clamp-free fast sigmoid/tanh (exp2/rcp saturate correctly at extremes)
__device__ __forceinline__ float sigm(float x) {
  return __builtin_amdgcn_rcpf(1.f + __builtin_amdgcn_exp2f(-L2E * x));
}
__device__ __forceinline__ float tanhc(float x) {
  return __builtin_fmaf(2.f, __builtin_amdgcn_rcpf(1.f + __builtin_amdgcn_exp2f((-2.f*L2E) * x)), -1.f);
}

__global__ __launch_bounds__(BLK, 2) void prnn_kernel(
    const float* __restrict__ x, const float* __restrict__ w_ih,
    const float* __restrict__ w_hh, const float* __restrict__ b_ih,
    const float* __restrict__ b_hh, const float* __restrict__ w1,
    const float* __restrict__ b1, const float* __restrict__ w2,
    const float* __restrict__ b2, float* __restrict__ out) {

  // all matrix LDS in fragment order: [frag][lane] x 16B
  __shared__ __align__(16) unsigned char lds_whhn[8*4*64*16];   // 32 KB  (n-gate A-frags)
  __shared__ __align__(16) unsigned char lds_h[4*2*64*16];      // 8 KB   (h B-frags)
  __shared__ __align__(16) unsigned char lds_hid[2*4*2*64*16];  // 16 KB  (hid B-frags, dbuf)
  __shared__ __align__(16) unsigned char lds_w2f[4*64*16];      // 4 KB   (w2 A-frags)
  __shared__ __align__(16) float lds_xrz[64*4*4];               // 4 KB   xi table r,z (+both biases)
  __shared__ __align__(16) float lds_xn[32*4*4];                // 2 KB   xi table n (b_ih only)
  __shared__ unsigned lds_idx[32*8];                            // 1 KB   packed patches
  __shared__ float lds_lp[4][32];

  const int tid = threadIdx.x;
  const int bbase = blockIdx.x * BT;
  const int lane = tid & 63;
  const int lg = lane >> 4, ln = lane & 15;
  const int js = __builtin_amdgcn_readfirstlane(tid >> 6);   // wave id 0..3

  // ---- init: patch indices, 4 per u32 ----
  {
    int b = tid >> 3, ch = tid & 7;
    const float* xp = x + (size_t)(bbase + b) * 64 + ch * 8;
    float4 v0 = *(const float4*)xp, v1 = *(const float4*)(xp + 4);
    unsigned pk = ((v0.x!=0.f?1u:0u) | (v0.y!=0.f?2u:0u))
               | (((v0.z!=0.f?1u:0u) | (v0.w!=0.f?2u:0u)) << 8)
               | (((v1.x!=0.f?1u:0u) | (v1.y!=0.f?2u:0u)) << 16)
               | (((v1.z!=0.f?1u:0u) | (v1.w!=0.f?2u:0u)) << 24);
    lds_idx[b*8 + ch] = pk;
  }
  // ---- init: xi tables ----
  {
    int j = tid;                                  // rows 0..255 (r,z): fold b_ih+b_hh
    float base = b_ih[j] + b_hh[j];
    float wa = w_ih[2*j], wb = w_ih[2*j+1];
    int q = j >> 2, e = j & 3;
    #pragma unroll
    for (int v = 0; v < 4; ++v)
      lds_xrz[(q*4+v)*4 + e] = base + ((v&1) ? wa : 0.f) + ((v&2) ? wb : 0.f);
    if (tid < 128) {                              // rows 256..383 (n): b_ih only
      int j2 = 256 + tid;
      float bn = b_ih[j2];
      float wan = w_ih[2*j2], wbn = w_ih[2*j2+1];
      int qn = tid >> 2, en = tid & 3;
      #pragma unroll
      for (int v = 0; v < 4; ++v)
        lds_xn[(qn*4+v)*4 + en] = bn + ((v&1) ? wan : 0.f) + ((v&2) ? wbn : 0.f);
    }
  }
  // ---- init: w_hh(n) A-frags into LDS, fragment order ----
  #pragma unroll
  for (int it = 0; it < 8; ++it) {
    int i = tid + it * 256;                       // 0..2047 = [mt(8)][ks(4)][lane(64)]
    int mt = i >> 8, ks = (i >> 6) & 3, l = i & 63;
    int lgg = l >> 4, lnn = l & 15;
    const float* src = w_hh + (256 + 16*mt + lnn) * 128 + ks*32 + lgg*8;
    s8v fr = pack8(*(const float4*)src, *(const float4*)(src + 4));
    *(s8v*)(lds_whhn + ((mt*4 + ks)*64 + l) * 16) = fr;
  }
  // ---- init: w2 A-frags into LDS (rows 0..3 real, rest zero) ----
  {
    int ks = tid >> 6, l = tid & 63;
    int lgg = l >> 4, lnn = l & 15;
    s8v fr;
    #pragma unroll
    for (int e = 0; e < 8; ++e) fr[e] = (short)0;
    if (lnn < 4) {
      const float* src = w2 + lnn * 128 + ks*32 + lgg*8;
      fr = pack8(*(const float4*)src, *(const float4*)(src + 4));
    }
    *(s8v*)(lds_w2f + (ks*64 + l) * 16) = fr;
  }

  // ---- register preloads: w_hh(r,z), w1 A-frags; biases ----
  s8v Ar[2][4], Az[2][4], wA1[2][4];
  f4v bhn2[2], b1f[2], b2r;
  #pragma unroll
  for (int p = 0; p < 2; ++p) {
    int row = 32*js + 16*p + ln;
    #pragma unroll
    for (int ks = 0; ks < 4; ++ks) {
      const float* s0 = w_hh + row * 128 + ks*32 + lg*8;           // r rows 0..127
      Ar[p][ks] = pack8(*(const float4*)s0, *(const float4*)(s0 + 4));
      const float* s1 = w_hh + (128 + row) * 128 + ks*32 + lg*8;   // z rows 128..255
      Az[p][ks] = pack8(*(const float4*)s1, *(const float4*)(s1 + 4));
      const float* s2 = w1 + row * 128 + ks*32 + lg*8;
      wA1[p][ks] = pack8(*(const float4*)s2, *(const float4*)(s2 + 4));
    }
    int jr = 32*js + 16*p + 4*lg;
    bhn2[p] = *(const f4v*)(b_hh + 256 + jr);
    b1f[p]  = *(const f4v*)(b1 + jr);
  }
  if (lg == 0) b2r = *(const f4v*)b2;
  else { b2r[0]=0.f; b2r[1]=0.f; b2r[2]=0.f; b2r[3]=0.f; }

  __syncthreads();

  // ---- per-lane packed patch history for cols ln and 16+ln (2 bits/step) ----
  unsigned pk0a=0, pk0b=0, pk1a=0, pk1b=0;
  #pragma unroll
  for (int w8 = 0; w8 < 4; ++w8) {
    unsigned u = lds_idx[ln*8 + w8];
    pk0a |= (((u&3u) | ((u>>6)&0xCu) | ((u>>12)&0x30u) | ((u>>18)&0xC0u)) << (8*w8));
    unsigned u2 = lds_idx[(16+ln)*8 + w8];
    pk1a |= (((u2&3u) | ((u2>>6)&0xCu) | ((u2>>12)&0x30u) | ((u2>>18)&0xC0u)) << (8*w8));
  }
  #pragma unroll
  for (int w8 = 4; w8 < 8; ++w8) {
    unsigned u = lds_idx[ln*8 + w8];
    pk0b |= (((u&3u) | ((u>>6)&0xCu) | ((u>>12)&0x30u) | ((u>>18)&0xC0u)) << (8*(w8-4)));
    unsigned u2 = lds_idx[(16+ln)*8 + w8];
    pk1b |= (((u2&3u) | ((u2>>6)&0xCu) | ((u2>>12)&0x30u) | ((u2>>18)&0xC0u)) << (8*(w8-4)));
  }

  const f4v* XRZ = (const f4v*)lds_xrz;
  const f4v* XN  = (const f4v*)lds_xn;

  s8v Bf[4][2];                      // h B-frags, carried P4(t) -> P1(t+1); h0 = 0
  #pragma unroll
  for (int ks = 0; ks < 4; ++ks)
    #pragma unroll
    for (int nt = 0; nt < 2; ++nt)
      #pragma unroll
      for (int e = 0; e < 8; ++e) Bf[ks][nt][e] = (short)0;
  f4v hfr[2][2];                     // h C-frags (for z*(h-n)+n)
  #pragma unroll
  for (int p = 0; p < 2; ++p)
    #pragma unroll
    for (int nt = 0; nt < 2; ++nt) { hfr[p][nt][0]=0.f; hfr[p][nt][1]=0.f; hfr[p][nt][2]=0.f; hfr[p][nt][3]=0.f; }
  float lp0 = 0.f, lp1 = 0.f;
  int pv0 = 0, pv1 = 0;

  for (int tb = 0; tb < NSTEP; tb += 4) {
    #pragma unroll
    for (int k = 0; k < 4; ++k) {
      const int t = tb + k;
      // ---- P1: gh MFMAs (acc init = xi / b_hh_n) + gates + h C-frag write ----
      uint2 hwv[2][2];
      #pragma unroll
      for (int nt = 0; nt < 2; ++nt) {
        const int var = nt ? pv1 : pv0;
        f4v aR[2], aZ[2], aN[2], xnv[2];
        #pragma unroll
        for (int p = 0; p < 2; ++p) {
          const int q = 8*js + 4*p + lg;
          aR[p]  = XRZ[(q     )*4 + var];
          aZ[p]  = XRZ[(q + 32)*4 + var];
          xnv[p] = XN [(q     )*4 + var];
          aN[p]  = bhn2[p];
        }
        #pragma unroll
        for (int ks = 0; ks < 4; ++ks) {
          s8v An0 = *(const s8v*)(lds_whhn + (((2*js+0)*4 + ks)*64 + lane)*16);
          s8v An1 = *(const s8v*)(lds_whhn + (((2*js+1)*4 + ks)*64 + lane)*16);
          aR[0] = mfma16(Ar[0][ks], Bf[ks][nt], aR[0]);
          aR[1] = mfma16(Ar[1][ks], Bf[ks][nt], aR[1]);
          aZ[0] = mfma16(Az[0][ks], Bf[ks][nt], aZ[0]);
          aZ[1] = mfma16(Az[1][ks], Bf[ks][nt], aZ[1]);
          aN[0] = mfma16(An0,       Bf[ks][nt], aN[0]);
          aN[1] = mfma16(An1,       Bf[ks][nt], aN[1]);
        }
        #pragma unroll
        for (int p = 0; p < 2; ++p) {
          f4v hn;
          #pragma unroll
          for (int r = 0; r < 4; ++r) {
            float R  = sigm(aR[p][r]);
            float Z  = sigm(aZ[p][r]);
            float Ng = tanhc(__builtin_fmaf(R, aN[p][r], xnv[p][r]));
            hn[r] = __builtin_fmaf(Z, hfr[p][nt][r] - Ng, Ng);
          }
          hfr[p][nt] = hn;
          hwv[p][nt].x = pkbf2(hn[0], hn[1]);
          hwv[p][nt].y = pkbf2(hn[2], hn[3]);
        }
      }
      #pragma unroll
      for (int p = 0; p < 2; ++p) {
        const int lgp = (2*p + (lg >> 1)) & 3;      // C-frag -> B-frag position
        #pragma unroll
        for (int nt = 0; nt < 2; ++nt)
          *(uint2*)(lds_h + (((js*2 + nt)*64) + lgp*16 + ln)*16 + 8*(lg & 1)) = hwv[p][nt];
      }
      __syncthreads();                               // B1: h complete
      // ---- P4: reload h B-frags (carried to next P1); hid = relu(W1 h + b1) ----
      #pragma unroll
      for (int ks = 0; ks < 4; ++ks)
        #pragma unroll
        for (int nt = 0; nt < 2; ++nt)
          Bf[ks][nt] = *(const s8v*)(lds_h + ((ks*2 + nt)*64 + lane)*16);
      f4v hc[2][2];
      #pragma unroll
      for (int p = 0; p < 2; ++p) { hc[p][0] = b1f[p]; hc[p][1] = b1f[p]; }
      #pragma unroll
      for (int ks = 0; ks < 4; ++ks)
        #pragma unroll
        for (int p = 0; p < 2; ++p) {
          hc[p][0] = mfma16(wA1[p][ks], Bf[ks][0], hc[p][0]);
          hc[p][1] = mfma16(wA1[p][ks], Bf[ks][1], hc[p][1]);
        }
      #pragma unroll
      for (int p = 0; p < 2; ++p) {
        const int lgp = (2*p + (lg >> 1)) & 3;
        #pragma unroll
        for (int nt = 0; nt < 2; ++nt) {
          uint2 wv;
          wv.x = pkbf2(fmaxf(hc[p][nt][0], 0.f), fmaxf(hc[p][nt][1], 0.f));
          wv.y = pkbf2(fmaxf(hc[p][nt][2], 0.f), fmaxf(hc[p][nt][3], 0.f));
          *(uint2*)(lds_hid + (k&1)*8192 + ((js*2 + nt)*64 + lgp*16 + ln)*16 + 8*(lg & 1)) = wv;
        }
      }
      __syncthreads();                               // B2: hid complete
      // ---- current patch (P5 gather + next step's input variant) ----
      const unsigned pc0 = (t & 16) ? pk0b : pk0a;
      const unsigned pc1 = (t & 16) ? pk1b : pk1a;
      const int sh  = (2*t) & 31;
      const int ic0 = (pc0 >> sh) & 3;
      const int ic1 = (pc1 >> sh) & 3;
      // ---- P5: logits + log-softmax gather (rotating wave; lg==0 lanes) ----
      if (js == k) {
        f4v la0 = b2r, la1 = b2r;
        #pragma unroll
        for (int ks = 0; ks < 4; ++ks) {
          s8v W2f = *(const s8v*)(lds_w2f + (ks*64 + lane)*16);
          s8v Bh0 = *(const s8v*)(lds_hid + (k&1)*8192 + ((ks*2 + 0)*64 + lane)*16);
          s8v Bh1 = *(const s8v*)(lds_hid + (k&1)*8192 + ((ks*2 + 1)*64 + lane)*16);
          la0 = mfma16(W2f, Bh0, la0);
          la1 = mfma16(W2f, Bh1, la1);
        }
        if (lg == 0) {
          {
            float l0=la0[0], l1=la0[1], l2=la0[2], l3=la0[3];
            float m = fmaxf(fmaxf(l0, l1), fmaxf(l2, l3));
            float s = __builtin_amdgcn_exp2f((l0-m)*L2E) + __builtin_amdgcn_exp2f((l1-m)*L2E)
                    + __builtin_amdgcn_exp2f((l2-m)*L2E) + __builtin_amdgcn_exp2f((l3-m)*L2E);
            float sel = (ic0 == 0) ? l0 : (ic0 == 1) ? l1 : (ic0 == 2) ? l2 : l3;
            lp0 += (sel - m) - __builtin_amdgcn_logf(s) * LN2;
          }
          {
            float l0=la1[0], l1=la1[1], l2=la1[2], l3=la1[3];
            float m = fmaxf(fmaxf(l0, l1), fmaxf(l2, l3));
            float s = __builtin_amdgcn_exp2f((l0-m)*L2E) + __builtin_amdgcn_exp2f((l1-m)*L2E)
                    + __builtin_amdgcn_exp2f((l2-m)*L2E) + __builtin_amdgcn_exp2f((l3-m)*L2E);
            float sel = (ic1 == 0) ? l0 : (ic1 == 1) ? l1 : (ic1 == 2) ? l2 : l3;
            lp1 += (sel - m) - __builtin_amdgcn_logf(s) * LN2;
          }
        }
      }
      pv0 = ic0; pv1 = ic1;
    }
  }

  // ---- cross-wave logp reduction ----
  if (lg == 0) { lds_lp[js][ln] = lp0; lds_lp[js][16 + ln] = lp1; }
  __syncthreads();
  if (tid < 32) {
    float s = lds_lp[0][tid] + lds_lp[1][tid] + lds_lp[2][tid] + lds_lp[3][tid];
    out[bbase + tid] = s;
  }
}

extern "C" void kernel_launch(void* const* d_in, const int* in_sizes, int n_in,
                              void* d_out, int out_size, void* d_ws, size_t ws_size,
                              hipStream_t stream) {
  const float* x    = (const float*)d_in[0];
  const float* w_ih = (const float*)d_in[1];
  const float* w_hh = (const float*)d_in[2];
  const float* b_ih = (const float*)d_in[3];
  const float* b_hh = (const float*)d_in[4];
  const float* w1   = (const float*)d_in[5];
  const float* b1   = (const float*)d_in[6];
  const float* w2   = (const float*)d_in[7];
  const float* b2   = (const float*)d_in[8];
  float* out = (float*)d_out;
  int B = in_sizes[0] / 64;          // 16384
  int grid = B / BT;                 // 512
  prnn_kernel<<<grid, BLK, 0, stream>>>(x, w_ih, w_hh, b_ih, b_hh, w1, b1, w2, b2, out);
}

// Round 3
// 100.017 us; speedup vs baseline: 1.8769x; 1.0543x over previous
//
#include <hip/hip_runtime.h>
#include <hip/hip_bf16.h>

// PRNN R3: GRU(NH=128, T=32) + MLP head, B=16384.
// 8 waves (512 thr) per 32-seq tile, grid=512. Each wave owns a 16-row j-slice
// of each gate -> 8 gate-elems/lane, 48 weight VGPRs. w_hh(r,z,n) A-frags in regs;
// w1/w2 A-frags in LDS (frag order, loop-invariant addresses). Single-buffered hid.
// Target: VGPR<=128 -> 2 blocks/CU = 4 waves/SIMD.

#define NSTEP 32
#define BT    32
#define BLK   512

using s8v = __attribute__((ext_vector_type(8))) short;   // 8 bf16
using f4v = __attribute__((ext_vector_type(4))) float;   // MFMA acc

#define L2E 1.4426950408889634f
#define LN2 0.6931471805599453f

__device__ __forceinline__ unsigned short f2bf(float f) {
  __hip_bfloat16 h = __float2bfloat16(f);
  return __builtin_bit_cast(unsigned short, h);
}
__device__ __forceinline__ unsigned pkbf2(float a, float b) {
  return (unsigned)f2bf(a) | ((unsigned)f2bf(b) << 16);
}
__device__ __forceinline__ s8v pack8(float4 u, float4 v) {
  s8v a;
  a[0]=(short)f2bf(u.x); a[1]=(short)f2bf(u.y); a[2]=(short)f2bf(u.z); a[3]=(short)f2bf(u.w);
  a[4]=(short)f2bf(v.x); a[5]=(short)f2bf(v.y); a[6]=(short)f2bf(v.z); a[7]=(short)f2bf(v.w);
  return a;
}
__device__ __forceinline__ f4v mfma16(s8v a, s8v b, f4v c) {
  return __builtin_amdgcn_mfma_f32_16x16x32_bf16(a, b, c, 0, 0, 0);
}
__device__ __forceinline__ float sigm(float x) {
  return __builtin_amdgcn_rcpf(1.f + __builtin_amdgcn_exp2f(-L2E * x));
}
__device__ __forceinline__ float tanhc(float x) {
  return __builtin_fmaf(2.f, __builtin_amdgcn_rcpf(1.f + __builtin_amdgcn_exp2f((-2.f*L2E) * x)), -1.f);
}

__global__ __launch_bounds__(BLK, 4) void prnn_kernel(
    const float* __restrict__ x, const float* __restrict__ w_ih,
    const float* __restrict__ w_hh, const float* __restrict__ b_ih,
    const float* __restrict__ b_hh, const float* __restrict__ w1,
    const float* __restrict__ b1, const float* __restrict__ w2,
    const float* __restrict__ b2, float* __restrict__ out) {

  __shared__ __align__(16) unsigned char lds_h[4*2*64*16];     // 8 KB  h B-frags
  __shared__ __align__(16) unsigned char lds_hid[4*2*64*16];   // 8 KB  hid B-frags
  __shared__ __align__(16) unsigned char lds_wA1[8*4*64*16];   // 32 KB w1 A-frags
  __shared__ __align__(16) unsigned char lds_w2f[4*64*16];     // 4 KB  w2 A-frags
  __shared__ __align__(16) float lds_xrz[64*4*4];              // 4 KB  xi r,z (+biases)
  __shared__ __align__(16) float lds_xn[32*4*4];               // 2 KB  xi n (b_ih only)
  __shared__ __align__(16) float lds_bb[256];                  // 1 KB  b_hh_n | b1
  __shared__ __align__(16) float lds_b2[4];
  __shared__ unsigned lds_idx[32*8];                           // 1 KB
  __shared__ float lds_lp[8][32];                              // 1 KB

  const int tid = threadIdx.x;
  const int bbase = blockIdx.x * BT;
  const int lane = tid & 63;
  const int lg = lane >> 4, ln = lane & 15;
  const int w = __builtin_amdgcn_readfirstlane(tid >> 6);   // wave 0..7

  // ---- init: patch indices (32 batch x 8 u32) ----
  if (tid < 256) {
    int b = tid >> 3, ch = tid & 7;
    const float* xp = x + (size_t)(bbase + b) * 64 + ch * 8;
    float4 v0 = *(const float4*)xp, v1 = *(const float4*)(xp + 4);
    unsigned pk = ((v0.x!=0.f?1u:0u) | (v0.y!=0.f?2u:0u))
               | (((v0.z!=0.f?1u:0u) | (v0.w!=0.f?2u:0u)) << 8)
               | (((v1.x!=0.f?1u:0u) | (v1.y!=0.f?2u:0u)) << 16)
               | (((v1.z!=0.f?1u:0u) | (v1.w!=0.f?2u:0u)) << 24);
    lds_idx[b*8 + ch] = pk;
  }
  // ---- init: xi tables ----
  if (tid < 256) {                              // rows 0..255 (r,z): fold b_ih+b_hh
    int j = tid;
    float base = b_ih[j] + b_hh[j];
    float wa = w_ih[2*j], wb = w_ih[2*j+1];
    int q = j >> 2, e = j & 3;
    #pragma unroll
    for (int v = 0; v < 4; ++v)
      lds_xrz[(q*4+v)*4 + e] = base + ((v&1) ? wa : 0.f) + ((v&2) ? wb : 0.f);
  }
  if (tid < 128) {                              // rows 256..383 (n): b_ih only
    int j2 = 256 + tid;
    float bn = b_ih[j2];
    float wan = w_ih[2*j2], wbn = w_ih[2*j2+1];
    int qn = tid >> 2, en = tid & 3;
    #pragma unroll
    for (int v = 0; v < 4; ++v)
      lds_xn[(qn*4+v)*4 + en] = bn + ((v&1) ? wan : 0.f) + ((v&2) ? wbn : 0.f);
  }
  // ---- init: bias tables ----
  if (tid < 128) lds_bb[tid] = b_hh[256 + tid];
  else if (tid < 256) lds_bb[tid] = b1[tid - 128];
  if (tid < 4) lds_b2[tid] = b2[tid];
  // ---- init: w1 A-frags, fragment order [mt][ks][lane] ----
  #pragma unroll
  for (int it = 0; it < 4; ++it) {
    int i = tid + it * BLK;                     // 0..2047
    int mt = i >> 8, ks = (i >> 6) & 3, l = i & 63;
    const float* src = w1 + (16*mt + (l & 15)) * 128 + ks*32 + (l >> 4)*8;
    *(s8v*)(lds_wA1 + ((mt*4 + ks)*64 + l)*16) = pack8(*(const float4*)src, *(const float4*)(src+4));
  }
  // ---- init: w2 A-frags (rows 0..3 real, rest zero) ----
  if (tid < 256) {
    int ks = tid >> 6, l = tid & 63;
    s8v fr;
    #pragma unroll
    for (int e = 0; e < 8; ++e) fr[e] = (short)0;
    if ((l & 15) < 4) {
      const float* src = w2 + (l & 15) * 128 + ks*32 + (l >> 4)*8;
      fr = pack8(*(const float4*)src, *(const float4*)(src + 4));
    }
    *(s8v*)(lds_w2f + (ks*64 + l)*16) = fr;
  }

  // ---- register weights: w_hh r/z/n A-frags for this wave's 16-row slice ----
  s8v Ar[4], Az[4], An[4];
  {
    const int row = 16*w + ln;
    #pragma unroll
    for (int ks = 0; ks < 4; ++ks) {
      const float* s0 = w_hh + row*128 + ks*32 + lg*8;
      Ar[ks] = pack8(*(const float4*)s0, *(const float4*)(s0 + 4));
      const float* s1 = s0 + 128*128;
      Az[ks] = pack8(*(const float4*)s1, *(const float4*)(s1 + 4));
      const float* s2 = s0 + 256*128;
      An[ks] = pack8(*(const float4*)s2, *(const float4*)(s2 + 4));
    }
  }

  __syncthreads();

  // ---- per-lane packed patch history for batch cols ln, 16+ln ----
  unsigned pk0a=0, pk0b=0, pk1a=0, pk1b=0;
  #pragma unroll
  for (int w8 = 0; w8 < 4; ++w8) {
    unsigned u = lds_idx[ln*8 + w8];
    pk0a |= (((u&3u) | ((u>>6)&0xCu) | ((u>>12)&0x30u) | ((u>>18)&0xC0u)) << (8*w8));
    unsigned u2 = lds_idx[(16+ln)*8 + w8];
    pk1a |= (((u2&3u) | ((u2>>6)&0xCu) | ((u2>>12)&0x30u) | ((u2>>18)&0xC0u)) << (8*w8));
  }
  #pragma unroll
  for (int w8 = 4; w8 < 8; ++w8) {
    unsigned u = lds_idx[ln*8 + w8];
    pk0b |= (((u&3u) | ((u>>6)&0xCu) | ((u>>12)&0x30u) | ((u>>18)&0xC0u)) << (8*(w8-4)));
    unsigned u2 = lds_idx[(16+ln)*8 + w8];
    pk1b |= (((u2&3u) | ((u2>>6)&0xCu) | ((u2>>12)&0x30u) | ((u2>>18)&0xC0u)) << (8*(w8-4)));
  }

  // C-frag -> B-frag write offset for this lane (h and hid share the pattern)
  const unsigned wroff = (unsigned)((((w>>1)*128) + 16*(2*(w&1) + (lg>>1)) + ln)*16 + 8*(lg&1));
  const int q = 4*w + lg;

  s8v Bf[4][2];
  #pragma unroll
  for (int ks = 0; ks < 4; ++ks)
    #pragma unroll
    for (int nt = 0; nt < 2; ++nt)
      #pragma unroll
      for (int e = 0; e < 8; ++e) Bf[ks][nt][e] = (short)0;
  f4v hfr[2];
  hfr[0][0]=0.f; hfr[0][1]=0.f; hfr[0][2]=0.f; hfr[0][3]=0.f;
  hfr[1] = hfr[0];
  float lp0 = 0.f, lp1 = 0.f;
  int pv0 = 0, pv1 = 0;

  for (int tb = 0; tb < NSTEP; tb += 8) {
    const unsigned pc0 = (tb & 16) ? pk0b : pk0a;
    const unsigned pc1 = (tb & 16) ? pk1b : pk1a;
    #pragma unroll
    for (int k = 0; k < 8; ++k) {
      const int t = tb + k;
      // ---- P1: gate MFMAs (C-init = xi) + gate math + h write ----
      const f4v aNi = *(const f4v*)&lds_bb[q*4];
      #pragma unroll
      for (int nt = 0; nt < 2; ++nt) {
        const int var = nt ? pv1 : pv0;
        f4v aR = *(const f4v*)&lds_xrz[(q*4 + var)*4];
        f4v aZ = *(const f4v*)&lds_xrz[((q+32)*4 + var)*4];
        f4v aN = aNi;
        #pragma unroll
        for (int ks = 0; ks < 4; ++ks) {
          aR = mfma16(Ar[ks], Bf[ks][nt], aR);
          aZ = mfma16(Az[ks], Bf[ks][nt], aZ);
          aN = mfma16(An[ks], Bf[ks][nt], aN);
        }
        const f4v xnv = *(const f4v*)&lds_xn[(q*4 + var)*4];
        f4v hn;
        #pragma unroll
        for (int r = 0; r < 4; ++r) {
          float R  = sigm(aR[r]);
          float Z  = sigm(aZ[r]);
          float Ng = tanhc(__builtin_fmaf(R, aN[r], xnv[r]));
          hn[r] = __builtin_fmaf(Z, hfr[nt][r] - Ng, Ng);
        }
        hfr[nt] = hn;
        uint2 wv;
        wv.x = pkbf2(hn[0], hn[1]);
        wv.y = pkbf2(hn[2], hn[3]);
        *(uint2*)(lds_h + wroff + (unsigned)(nt*1024)) = wv;
      }
      __syncthreads();                           // B1: h complete
      // ---- P4: reload h B-frags (feeds next P1); hid = relu(W1 h + b1) ----
      #pragma unroll
      for (int ks = 0; ks < 4; ++ks)
        #pragma unroll
        for (int nt = 0; nt < 2; ++nt)
          Bf[ks][nt] = *(const s8v*)(lds_h + ((ks*2 + nt)*64 + lane)*16);
      const f4v b1i = *(const f4v*)&lds_bb[128 + q*4];
      f4v hc0 = b1i, hc1 = b1i;
      #pragma unroll
      for (int ks = 0; ks < 4; ++ks) {
        const s8v wf = *(const s8v*)(lds_wA1 + ((w*4 + ks)*64 + lane)*16);
        hc0 = mfma16(wf, Bf[ks][0], hc0);
        hc1 = mfma16(wf, Bf[ks][1], hc1);
      }
      {
        uint2 wv;
        wv.x = pkbf2(fmaxf(hc0[0],0.f), fmaxf(hc0[1],0.f));
        wv.y = pkbf2(fmaxf(hc0[2],0.f), fmaxf(hc0[3],0.f));
        *(uint2*)(lds_hid + wroff) = wv;
        wv.x = pkbf2(fmaxf(hc1[0],0.f), fmaxf(hc1[1],0.f));
        wv.y = pkbf2(fmaxf(hc1[2],0.f), fmaxf(hc1[3],0.f));
        *(uint2*)(lds_hid + wroff + 1024u) = wv;
      }
      __syncthreads();                           // B2: hid complete
      // ---- current patch ----
      const int sh  = (2*t) & 31;
      const int ic0 = (int)((pc0 >> sh) & 3);
      const int ic1 = (int)((pc1 >> sh) & 3);
      // ---- P5: logits + log-softmax gather (rotating wave) ----
      if (w == k) {
        const f4v b2v = *(const f4v*)lds_b2;
        f4v la0, la1;
        #pragma unroll
        for (int r = 0; r < 4; ++r) {
          la0[r] = (lg == 0) ? b2v[r] : 0.f;
          la1[r] = la0[r];
        }
        #pragma unroll
        for (int ks = 0; ks < 4; ++ks) {
          const s8v W2f = *(const s8v*)(lds_w2f + (ks*64 + lane)*16);
          la0 = mfma16(W2f, *(const s8v*)(lds_hid + ((ks*2 + 0)*64 + lane)*16), la0);
          la1 = mfma16(W2f, *(const s8v*)(lds_hid + ((ks*2 + 1)*64 + lane)*16), la1);
        }
        if (lg == 0) {
          {
            float l0=la0[0], l1=la0[1], l2=la0[2], l3=la0[3];
            float m = fmaxf(fmaxf(l0, l1), fmaxf(l2, l3));
            float s = __builtin_amdgcn_exp2f((l0-m)*L2E) + __builtin_amdgcn_exp2f((l1-m)*L2E)
                    + __builtin_amdgcn_exp2f((l2-m)*L2E) + __builtin_amdgcn_exp2f((l3-m)*L2E);
            float sel = (ic0 == 0) ? l0 : (ic0 == 1) ? l1 : (ic0 == 2) ? l2 : l3;
            lp0 += (sel - m) - __builtin_amdgcn_logf(s) * LN2;
          }
          {
            float l0=la1[0], l1=la1[1], l2=la1[2], l3=la1[3];
            float m = fmaxf(fmaxf(l0, l1), fmaxf(l2, l3));
            float s = __builtin_amdgcn_exp2f((l0-m)*L2E) + __builtin_amdgcn_exp2f((l1-m)*L2E)
                    + __builtin_amdgcn_exp2f((l2-m)*L2E) + __builtin_amdgcn_exp2f((l3-m)*L2E);
            float sel = (ic1 == 0) ? l0 : (ic1 == 1) ? l1 : (ic1 == 2) ? l2 : l3;
            lp1 += (sel - m) - __builtin_amdgcn_logf(s) * LN2;
          }
        }
      }
      pv0 = ic0; pv1 = ic1;
    }
  }

  // ---- cross-wave logp reduction ----
  if (lg == 0) { lds_lp[w][ln] = lp0; lds_lp[w][16 + ln] = lp1; }
  __syncthreads();
  if (tid < 32) {
    float s = 0.f;
    #pragma unroll
    for (int ww = 0; ww < 8; ++ww) s += lds_lp[ww][tid];
    out[bbase + tid] = s;
  }
}

extern "C" void kernel_launch(void* const* d_in, const int* in_sizes, int n_in,
                              void* d_out, int out_size, void* d_ws, size_t ws_size,
                              hipStream_t stream) {
  const float* x    = (const float*)d_in[0];
  const float* w_ih = (const float*)d_in[1];
  const float* w_hh = (const float*)d_in[2];
  const float* b_ih = (const float*)d_in[3];
  const float* b_hh = (const float*)d_in[4];
  const float* w1   = (const float*)d_in[5];
  const float* b1   = (const float*)d_in[6];
  const float* w2   = (const float*)d_in[7];
  const float* b2   = (const float*)d_in[8];
  float* out = (float*)d_out;
  int B = in_sizes[0] / 64;          // 16384
  int grid = B / BT;                 // 512
  prnn_kernel<<<grid, BLK, 0, stream>>>(x, w_ih, w_hh, b_ih, b_hh, w1, b1, w2, b2, out);
}